// Round 1
// baseline (108.007 us; speedup 1.0000x reference)
//
#include <hip/hip_runtime.h>

// ---------------------------------------------------------------------------
// LinearSelfAttention: out = Q@state + tril(Q Q^T,-1)@V ; new_state = state + Q^T V
// B=4 T=2048 nh=8 N=64 D=128.  3-dispatch CHUNK-GRANULAR decomposition, chunk=64:
//   phase1:  S_c[i][d] = sum_{t in chunk} Q[t][i] V[t][d]   (fp32 ws1, [i][d])
//   prefix:  P_c = state + sum_{c'<c} S_c'  (bf16 ws2, [i][d]); new_state fp32
//   phase2:  per chunk c (independent!): O = Q_c@P_c + tril(Q_c Q_c^T,-1)@V_c
// R3 vs R2: segment 128 -> chunk 64.  Phase2's in-kernel state update (update
// MFMAs + scalar Pt RMW + 2 barriers) is GONE; chunks fully parallel.  Grids
// double to 1024 -> phase1 16 waves/CU, phase2 12 waves/CU (was 8).
// All MFMA = f32_16x16x32_bf16.  C/D: col=lane&15, row=quad*4+reg (m89-verified).
// A frag: A[m=lane&15][k=quad*8+j]; B frag: B[k=quad*8+j][n=lane&15].
// ---------------------------------------------------------------------------

using floatx4 = __attribute__((ext_vector_type(4))) float;
using float4v = __attribute__((ext_vector_type(4))) float;
using shortx8 = __attribute__((ext_vector_type(8))) short;
using shortx4 = __attribute__((ext_vector_type(4))) short;
using uint2v  = __attribute__((ext_vector_type(2))) unsigned int;

#define MFMA16(a, b, c) __builtin_amdgcn_mfma_f32_16x16x32_bf16((a), (b), (c), 0, 0, 0)

__device__ __forceinline__ unsigned short f2bf(float f) {
  unsigned int u = __builtin_bit_cast(unsigned int, f);
  u += 0x7FFFu + ((u >> 16) & 1u);   // RNE
  return (unsigned short)(u >> 16);
}
__device__ __forceinline__ float bf2f(unsigned short h) {
  unsigned int u = ((unsigned int)h) << 16;
  return __builtin_bit_cast(float, u);
}
__device__ __forceinline__ unsigned int pack2(float a, float b) {
  return (unsigned int)f2bf(a) | ((unsigned int)f2bf(b) << 16);
}
// 8 consecutive bf16 from LDS, 8B-aligned (2x ds_read_b64)
__device__ __forceinline__ shortx8 lds8(const unsigned short* p) {
  shortx4 a = *(const shortx4*)p;
  shortx4 b = *(const shortx4*)(p + 4);
  return __builtin_shufflevector(a, b, 0, 1, 2, 3, 4, 5, 6, 7);
}

// ---------------------------------------------------------------------------
// Phase 1: S_c[i][d] = sum_{t in chunk} Q[t][i] V[t][d].  grid 1024, block 256.
// Qt[i][t], Vt[d][t], ld=68 shorts (34 u32): write stride 136B -> 2-way max
// (free), b64 reads 2-way max.  D[m=i][n=d]: A=Qt rows, B=Vt rows.  K=64.
// LDS 26.1 KB -> grid-limited 4 blocks/CU = 16 waves/CU.
// ---------------------------------------------------------------------------
__global__ __launch_bounds__(256) void k_phase1(const float* __restrict__ Q,
                                                const float* __restrict__ V,
                                                float* __restrict__ ws1) {
  __shared__ unsigned short Qt[64 * 68];    // [i][t]
  __shared__ unsigned short Vt[128 * 68];   // [d][t]

  const int id = blockIdx.x;
  const int n = id >> 7, bc = id & 127, b = bc >> 5, c = bc & 31;  // XCD swizzle:
  const int t0 = c * 64;            // fixed (b,c), all 8 n -> ids 128 apart -> same XCD
  const int tid = threadIdx.x;

  const float* qbase = Q + (((size_t)(b * 2048 + t0) * 8 + n) * 64);
  const float* vbase = V + ((size_t)(b * 2048 + t0) * 128);

  // convert-transpose staging: coalesced dword loads, paired-t u32 LDS writes
#pragma unroll
  for (int it = 0; it < 8; ++it) {          // Q: 64i x 32 t-pairs
    int j = tid + it * 256;
    int i = j & 63, p = j >> 6;
    float q0 = qbase[(2 * p) * 512 + i];
    float q1 = qbase[(2 * p + 1) * 512 + i];
    *(unsigned int*)&Qt[i * 68 + 2 * p] = pack2(q0, q1);
  }
#pragma unroll 8
  for (int it = 0; it < 16; ++it) {         // V: 128d x 32 t-pairs
    int j = tid + it * 256;
    int d = j & 127, p = j >> 7;
    float v0 = vbase[(2 * p) * 128 + d];
    float v1 = vbase[(2 * p + 1) * 128 + d];
    *(unsigned int*)&Vt[d * 68 + 2 * p] = pack2(v0, v1);
  }
  __syncthreads();

  const int wave = tid >> 6, lane = tid & 63;
  const int col = lane & 15, quad = lane >> 4;

  // wave -> d-tiles {2w,2w+1}, all 4 i-tiles.  K = 64 over t.
  floatx4 acc[4][2];
#pragma unroll
  for (int ti = 0; ti < 4; ++ti)
#pragma unroll
    for (int dj = 0; dj < 2; ++dj) acc[ti][dj] = (floatx4){0.f, 0.f, 0.f, 0.f};

#pragma unroll
  for (int s = 0; s < 2; ++s) {
    const int koff = s * 32 + quad * 8;
    shortx8 bv[2];
#pragma unroll
    for (int dj = 0; dj < 2; ++dj)
      bv[dj] = lds8(&Vt[((wave * 2 + dj) * 16 + col) * 68 + koff]);
#pragma unroll
    for (int ti = 0; ti < 4; ++ti) {
      shortx8 aq = lds8(&Qt[(ti * 16 + col) * 68 + koff]);
#pragma unroll
      for (int dj = 0; dj < 2; ++dj) acc[ti][dj] = MFMA16(aq, bv[dj], acc[ti][dj]);
    }
  }

  float* wbase = ws1 + (size_t)((b * 8 + n) * 32 + c) * 8192;
#pragma unroll
  for (int ti = 0; ti < 4; ++ti)
#pragma unroll
    for (int dj = 0; dj < 2; ++dj)
#pragma unroll
      for (int r = 0; r < 4; ++r) {
        int i = ti * 16 + quad * 4 + r;
        int d = (wave * 2 + dj) * 16 + col;
        wbase[i * 128 + d] = acc[ti][dj][r];
      }
}

// ---------------------------------------------------------------------------
// Prefix over 32 chunks, [i][d] layout: ALL accesses coalesced.
// grid 1024, block 256.  ws1 reads L3-resident (33.6 MB).
// ---------------------------------------------------------------------------
__global__ __launch_bounds__(256) void k_prefix(const float* __restrict__ state,
                                                const float* __restrict__ ws1,
                                                unsigned short* __restrict__ ws2,
                                                float* __restrict__ new_state) {
  int t = blockIdx.x * 256 + threadIdx.x;   // 0 .. 262143
  int bn = t >> 13;
  int e = t & 8191;                          // e = i*128 + d
  float run = state[bn * 8192 + e];
  const float* w1 = ws1 + (size_t)bn * 262144 + e;
  unsigned short* w2 = ws2 + (size_t)bn * 262144 + e;
#pragma unroll
  for (int g = 0; g < 32; ++g) {
    w2[g * 8192] = f2bf(run);
    run += w1[g * 8192];
  }
  new_state[bn * 8192 + e] = run;
}

// ---------------------------------------------------------------------------
// Phase 2: per (b,n,c), ONE independent 64-chunk:
//   O = Q_c @ P_c + tril(Q_c Q_c^T,-1) @ V_c      (no in-kernel state update)
// LDS 52 KB -> 3 blocks/CU = 12 waves/CU.  2 barriers total.
// Vt/Pt ld=68 (34 u32), Qs/Ss ld=72 (b128 rows).
// ---------------------------------------------------------------------------
__global__ __launch_bounds__(256) void k_phase2(const float* __restrict__ Q,
                                                const float* __restrict__ V,
                                                const unsigned short* __restrict__ ws2,
                                                float* __restrict__ out) {
  __shared__ unsigned short Qs[64 * 72];    // [t][k]  A-rows b128
  __shared__ unsigned short Vt[128 * 68];   // [d][u]  B rows b64x2
  __shared__ unsigned short Ss[64 * 72];    // [t][u]  masked scores, A-rows b128
  __shared__ unsigned short Pt[128 * 68];   // [d][i]  chunk state, B rows b64x2

  const int id = blockIdx.x;
  const int n = id >> 7, bc = id & 127, b = bc >> 5, c = bc & 31;  // XCD swizzle
  const int t0 = c * 64;
  const int tid = threadIdx.x;
  const int wave = tid >> 6, lane = tid & 63;
  const int col = lane & 15, quad = lane >> 4;

  // stage Pt: transpose ws2 [i][d] -> Pt[d][i]
  {
    const unsigned int* pb32 =
        (const unsigned int*)(ws2 + (size_t)((b * 8 + n) * 32 + c) * 8192);
#pragma unroll 8
    for (int it = 0; it < 16; ++it) {
      int j = tid + it * 256;
      int d2 = j & 63, i = j >> 6;
      unsigned int u = pb32[i * 64 + d2];   // coalesced: d2 fastest
      Pt[(2 * d2) * 68 + i] = (unsigned short)(u & 0xFFFFu);
      Pt[(2 * d2 + 1) * 68 + i] = (unsigned short)(u >> 16);
    }
  }

  const float* qbase = Q + (((size_t)(b * 2048 + t0) * 8 + n) * 64);
  const float* vbase = V + ((size_t)(b * 2048 + t0) * 128);
  float* obase = out + (((size_t)(b * 2048 + t0) * 8 + n) * 128);

  // ---- stage Qs [t][k] (b64 writes) and Vt [d][u] (convert-transpose) ----
#pragma unroll
  for (int it = 0; it < 4; ++it) {
    int l = tid + it * 256;
    int t = l >> 4, k4 = (l & 15) * 4;
    float4v q = *(const float4v*)(qbase + (size_t)t * 512 + k4);
    uint2v u;
    u.x = pack2(q.x, q.y);
    u.y = pack2(q.z, q.w);
    *(uint2v*)&Qs[t * 72 + k4] = u;
  }
#pragma unroll 8
  for (int it = 0; it < 16; ++it) {
    int j = tid + it * 256;
    int d = j & 127, p = j >> 7;            // u = 2p, 2p+1
    float v0 = vbase[(size_t)(2 * p) * 128 + d];
    float v1 = vbase[(size_t)(2 * p + 1) * 128 + d];
    *(unsigned int*)&Vt[d * 68 + 2 * p] = pack2(v0, v1);
  }
  __syncthreads();   // B1

  // ---- scores: S[t][u] = Q Q^T, strict-causal mask -> Ss ----
  {
    int job = 0;
    for (int ti = 0; ti < 4; ++ti)
      for (int ui = 0; ui <= (ti | 1); ++ui, ++job) {
        if ((job & 3) != wave) continue;
        if (ui > ti) {                      // masked tile read by K-loop: zero
#pragma unroll
          for (int r = 0; r < 4; ++r)
            Ss[(ti * 16 + quad * 4 + r) * 72 + ui * 16 + col] = 0;
        } else {
          floatx4 sc = (floatx4){0.f, 0.f, 0.f, 0.f};
#pragma unroll
          for (int s = 0; s < 2; ++s) {
            shortx8 at = *(const shortx8*)&Qs[(ti * 16 + col) * 72 + s * 32 + quad * 8];
            shortx8 au = *(const shortx8*)&Qs[(ui * 16 + col) * 72 + s * 32 + quad * 8];
            sc = MFMA16(at, au, sc);
          }
#pragma unroll
          for (int r = 0; r < 4; ++r) {
            int t = ti * 16 + quad * 4 + r, u = ui * 16 + col;
            Ss[t * 72 + u] = (u < t) ? f2bf(sc[r]) : (unsigned short)0;
          }
        }
      }
  }
  __syncthreads();   // B2

  // ---- O accum: wave -> d-tiles {2w,2w+1}, all 4 t-tiles ----
  floatx4 acc[4][2];
#pragma unroll
  for (int ti = 0; ti < 4; ++ti)
#pragma unroll
    for (int dj = 0; dj < 2; ++dj) acc[ti][dj] = (floatx4){0.f, 0.f, 0.f, 0.f};

  // Q @ P (K=64 over i)
#pragma unroll
  for (int s = 0; s < 2; ++s) {
    const int koff = s * 32 + quad * 8;
    shortx8 bp[2];
#pragma unroll
    for (int dj = 0; dj < 2; ++dj)
      bp[dj] = lds8(&Pt[((wave * 2 + dj) * 16 + col) * 68 + koff]);
#pragma unroll
    for (int ti = 0; ti < 4; ++ti) {
      shortx8 aq = *(const shortx8*)&Qs[(ti * 16 + col) * 72 + koff];
#pragma unroll
      for (int dj = 0; dj < 2; ++dj) acc[ti][dj] = MFMA16(aq, bp[dj], acc[ti][dj]);
    }
  }
  // S @ V (skip all-zero upper K-steps)
#pragma unroll
  for (int s = 0; s < 2; ++s) {
    const int koff = s * 32 + quad * 8;
    shortx8 bv[2];
#pragma unroll
    for (int dj = 0; dj < 2; ++dj)
      bv[dj] = lds8(&Vt[((wave * 2 + dj) * 16 + col) * 68 + koff]);
    for (int ti = (s == 0 ? 0 : 2); ti < 4; ++ti) {
      shortx8 as = *(const shortx8*)&Ss[(ti * 16 + col) * 72 + koff];
#pragma unroll
      for (int dj = 0; dj < 2; ++dj) acc[ti][dj] = MFMA16(as, bv[dj], acc[ti][dj]);
    }
  }
  // store O chunk
#pragma unroll
  for (int ti = 0; ti < 4; ++ti)
#pragma unroll
    for (int dj = 0; dj < 2; ++dj)
#pragma unroll
      for (int r = 0; r < 4; ++r) {
        int t = ti * 16 + quad * 4 + r;
        int d = (wave * 2 + dj) * 16 + col;
        obase[(size_t)t * 1024 + d] = acc[ti][dj][r];
      }
}

// ---------------------------------------------------------------------------
extern "C" void kernel_launch(void* const* d_in, const int* in_sizes, int n_in,
                              void* d_out, int out_size, void* d_ws, size_t ws_size,
                              hipStream_t stream) {
  (void)in_sizes; (void)n_in; (void)out_size; (void)ws_size;
  const float* Q     = (const float*)d_in[0];
  const float* V     = (const float*)d_in[1];
  const float* state = (const float*)d_in[2];
  float* out        = (float*)d_out;
  float* new_state  = out + (size_t)4 * 2048 * 8 * 128;
  float* ws1        = (float*)d_ws;                                        // 33.6 MB fp32 [i][d]
  unsigned short* ws2 = (unsigned short*)((char*)d_ws + (size_t)1024 * 8192 * 4);  // 16.8 MB bf16

  k_phase1<<<1024, 256, 0, stream>>>(Q, V, ws1);
  k_prefix<<<1024, 256, 0, stream>>>(state, ws1, ws2, new_state);
  k_phase2<<<1024, 256, 0, stream>>>(Q, V, ws2, out);
}

// Round 2
// 101.358 us; speedup vs baseline: 1.0656x; 1.0656x over previous
//
#include <hip/hip_runtime.h>

// ---------------------------------------------------------------------------
// LinearSelfAttention: out = Q@state + tril(Q Q^T,-1)@V ; new_state = state + Q^T V
// B=4 T=2048 nh=8 N=64 D=128.  3-dispatch chunked decomposition, segment=128:
//   phase1:  S_g[i][d] = sum_{t in seg} Q[t][i] V[t][d]   (bf16 ws1, [i][d])
//   prefix:  P_g = state + sum_{g'<g} S_g'  (bf16 ws2, [i][d]); new_state fp32
//   phase2:  per 64-chunk c: O = Q_c@P + tril(Q_c Q_c^T,-1)@V_c ; P += Q_c^T V_c
// R4 vs R0(=R2): ws1 stored bf16 (paired u32 stores via shfl_xor) -- cuts
// 25 MB of L3-resident scan traffic.  Kernels are BW-bound at ~floor; timed
// region also contains 2x 256MiB harness poison fills (~86us fixed).
// All MFMA = f32_16x16x32_bf16.  C/D: col=lane&15, row=quad*4+reg (m89-verified).
// A frag: A[m=lane&15][k=quad*8+j]; B frag: B[k=quad*8+j][n=lane&15].
// ---------------------------------------------------------------------------

using floatx4 = __attribute__((ext_vector_type(4))) float;
using float4v = __attribute__((ext_vector_type(4))) float;
using shortx8 = __attribute__((ext_vector_type(8))) short;
using shortx4 = __attribute__((ext_vector_type(4))) short;
using uint2v  = __attribute__((ext_vector_type(2))) unsigned int;

#define MFMA16(a, b, c) __builtin_amdgcn_mfma_f32_16x16x32_bf16((a), (b), (c), 0, 0, 0)

__device__ __forceinline__ unsigned short f2bf(float f) {
  unsigned int u = __builtin_bit_cast(unsigned int, f);
  u += 0x7FFFu + ((u >> 16) & 1u);   // RNE
  return (unsigned short)(u >> 16);
}
__device__ __forceinline__ float bf2f(unsigned short h) {
  unsigned int u = ((unsigned int)h) << 16;
  return __builtin_bit_cast(float, u);
}
__device__ __forceinline__ unsigned int pack2(float a, float b) {
  return (unsigned int)f2bf(a) | ((unsigned int)f2bf(b) << 16);
}
// 8 consecutive bf16 from LDS, 8B-aligned (2x ds_read_b64)
__device__ __forceinline__ shortx8 lds8(const unsigned short* p) {
  shortx4 a = *(const shortx4*)p;
  shortx4 b = *(const shortx4*)(p + 4);
  return __builtin_shufflevector(a, b, 0, 1, 2, 3, 4, 5, 6, 7);
}

// ---------------------------------------------------------------------------
// Phase 1: S_g[i][d] = sum_t Q[t][i] V[t][d].  grid 512, block 256.
// Qt[i][t], Vt[d][t], ld=132 shorts.  D[m=i][n=d]: A=Qt rows, B=Vt rows.
// ws1 written bf16: adjacent-d pairs combined via shfl_xor(1), even lanes
// store u32 -> halves ws1 traffic vs fp32.
// ---------------------------------------------------------------------------
__global__ __launch_bounds__(256) void k_phase1(const float* __restrict__ Q,
                                                const float* __restrict__ V,
                                                unsigned short* __restrict__ ws1) {
  __shared__ unsigned short Qt[64 * 132];   // [i][t]
  __shared__ unsigned short Vt[128 * 132];  // [d][t]

  const int id = blockIdx.x;
  const int n = id >> 6, bg = id & 63, b = bg >> 4, g = bg & 15;  // XCD swizzle
  const int t0 = g * 128;
  const int tid = threadIdx.x;

  const float* qbase = Q + (((size_t)(b * 2048 + t0) * 8 + n) * 64);
  const float* vbase = V + ((size_t)(b * 2048 + t0) * 128);

  // convert-transpose staging: coalesced dword loads, paired-t u32 LDS writes
#pragma unroll 8
  for (int it = 0; it < 16; ++it) {         // Q: 64i x 64 t-pairs
    int j = tid + it * 256;
    int i = j & 63, p = j >> 6;
    float q0 = qbase[(2 * p) * 512 + i];
    float q1 = qbase[(2 * p + 1) * 512 + i];
    *(unsigned int*)&Qt[i * 132 + 2 * p] = pack2(q0, q1);
  }
#pragma unroll 8
  for (int it = 0; it < 32; ++it) {         // V: 128d x 64 t-pairs
    int j = tid + it * 256;
    int d = j & 127, p = j >> 7;
    float v0 = vbase[(2 * p) * 128 + d];
    float v1 = vbase[(2 * p + 1) * 128 + d];
    *(unsigned int*)&Vt[d * 132 + 2 * p] = pack2(v0, v1);
  }
  __syncthreads();

  const int wave = tid >> 6, lane = tid & 63;
  const int col = lane & 15, quad = lane >> 4;

  // wave -> d-tiles {2w,2w+1}, all 4 i-tiles.  K = 128 over t.
  floatx4 acc[4][2];
#pragma unroll
  for (int ti = 0; ti < 4; ++ti)
#pragma unroll
    for (int dj = 0; dj < 2; ++dj) acc[ti][dj] = (floatx4){0.f, 0.f, 0.f, 0.f};

#pragma unroll
  for (int s = 0; s < 4; ++s) {
    const int koff = s * 32 + quad * 8;
    shortx8 bv[2];
#pragma unroll
    for (int dj = 0; dj < 2; ++dj)
      bv[dj] = lds8(&Vt[((wave * 2 + dj) * 16 + col) * 132 + koff]);
#pragma unroll
    for (int ti = 0; ti < 4; ++ti) {
      shortx8 aq = lds8(&Qt[(ti * 16 + col) * 132 + koff]);
#pragma unroll
      for (int dj = 0; dj < 2; ++dj) acc[ti][dj] = MFMA16(aq, bv[dj], acc[ti][dj]);
    }
  }

  // bf16 store: lane pairs (col, col^1) hold (d, d^1); even lane packs u32.
  unsigned short* wbase = ws1 + (size_t)((b * 8 + n) * 16 + g) * 8192;
#pragma unroll
  for (int ti = 0; ti < 4; ++ti)
#pragma unroll
    for (int dj = 0; dj < 2; ++dj)
#pragma unroll
      for (int r = 0; r < 4; ++r) {
        int i = ti * 16 + quad * 4 + r;
        int d = (wave * 2 + dj) * 16 + col;
        float f = acc[ti][dj][r];
        float fp = __shfl_xor(f, 1);        // partner holds d^1
        if ((lane & 1) == 0)
          *(unsigned int*)&wbase[i * 128 + d] = pack2(f, fp);
      }
}

// ---------------------------------------------------------------------------
// Prefix over 16 segments, [i][d] layout: ALL accesses coalesced.
// grid 1024, block 256.  ws1 bf16 reads (L3-resident), fp32 accumulate.
// ---------------------------------------------------------------------------
__global__ __launch_bounds__(256) void k_prefix(const float* __restrict__ state,
                                                const unsigned short* __restrict__ ws1,
                                                unsigned short* __restrict__ ws2,
                                                float* __restrict__ new_state) {
  int t = blockIdx.x * 256 + threadIdx.x;   // 0 .. 262143
  int bn = t >> 13;
  int e = t & 8191;                          // e = i*128 + d
  float run = state[bn * 8192 + e];
  const unsigned short* w1 = ws1 + (size_t)bn * 131072 + e;
  unsigned short* w2 = ws2 + (size_t)bn * 131072 + e;
#pragma unroll
  for (int g = 0; g < 16; ++g) {
    w2[g * 8192] = f2bf(run);
    run += bf2f(w1[g * 8192]);
  }
  new_state[bn * 8192 + e] = run;
}

// ---------------------------------------------------------------------------
// Phase 2: per (b,n,g): two 64-chunks.
//   O_c = Q_c @ P + tril(Q_c Q_c^T,-1) @ V_c ; after c=0: P += Q_0^T V_0.
// LDS 53.2 KB -> 3 blocks/CU.  Vt/Pt ld=68 (34 u32), Qs/Ss ld=72 (b128 rows).
// ---------------------------------------------------------------------------
__global__ __launch_bounds__(256) void k_phase2(const float* __restrict__ Q,
                                                const float* __restrict__ V,
                                                const unsigned short* __restrict__ ws2,
                                                float* __restrict__ out) {
  __shared__ unsigned short Qs[64 * 72];    // [t][k]  A-rows b128; update-B scalar cols
  __shared__ unsigned short Vt[128 * 68];   // [d][u]  B/A rows b64x2
  __shared__ unsigned short Ss[64 * 72];    // [t][u]  masked scores, A-rows b128
  __shared__ unsigned short Pt[128 * 68];   // [d][i]  running state, B rows b64x2

  const int id = blockIdx.x;
  const int n = id >> 6, bg = id & 63, b = bg >> 4, g = bg & 15;  // XCD swizzle
  const int t0 = g * 128;
  const int tid = threadIdx.x;
  const int wave = tid >> 6, lane = tid & 63;
  const int col = lane & 15, quad = lane >> 4;

  // stage Pt: transpose ws2 [i][d] -> Pt[d][i]
  {
    const unsigned int* pb32 =
        (const unsigned int*)(ws2 + (size_t)((b * 8 + n) * 16 + g) * 8192);
#pragma unroll 8
    for (int it = 0; it < 16; ++it) {
      int j = tid + it * 256;
      int d2 = j & 63, i = j >> 6;
      unsigned int u = pb32[i * 64 + d2];   // coalesced: d2 fastest
      Pt[(2 * d2) * 68 + i] = (unsigned short)(u & 0xFFFFu);
      Pt[(2 * d2 + 1) * 68 + i] = (unsigned short)(u >> 16);
    }
  }

  const float* qbase = Q + (((size_t)(b * 2048 + t0) * 8 + n) * 64);
  const float* vbase = V + ((size_t)(b * 2048 + t0) * 128);
  float* obase = out + (((size_t)(b * 2048 + t0) * 8 + n) * 128);

  for (int c = 0; c < 2; ++c) {
    // ---- stage Qs [t][k] (b64 writes) and Vt [d][u] (convert-transpose) ----
#pragma unroll
    for (int it = 0; it < 4; ++it) {
      int l = tid + it * 256;
      int t = l >> 4, k4 = (l & 15) * 4;
      float4v q = *(const float4v*)(qbase + (size_t)(c * 64 + t) * 512 + k4);
      uint2v u;
      u.x = pack2(q.x, q.y);
      u.y = pack2(q.z, q.w);
      *(uint2v*)&Qs[t * 72 + k4] = u;
    }
#pragma unroll 8
    for (int it = 0; it < 16; ++it) {
      int j = tid + it * 256;
      int d = j & 127, p = j >> 7;          // u = 2p, 2p+1
      float v0 = vbase[(size_t)(c * 64 + 2 * p) * 128 + d];
      float v1 = vbase[(size_t)(c * 64 + 2 * p + 1) * 128 + d];
      *(unsigned int*)&Vt[d * 68 + 2 * p] = pack2(v0, v1);
    }
    __syncthreads();   // B1

    // ---- scores: S[t][u] = Q Q^T, strict-causal mask -> Ss ----
    {
      int job = 0;
      for (int ti = 0; ti < 4; ++ti)
        for (int ui = 0; ui <= (ti | 1); ++ui, ++job) {
          if ((job & 3) != wave) continue;
          if (ui > ti) {                    // masked tile read by K-loop: zero
#pragma unroll
            for (int r = 0; r < 4; ++r)
              Ss[(ti * 16 + quad * 4 + r) * 72 + ui * 16 + col] = 0;
          } else {
            floatx4 sc = (floatx4){0.f, 0.f, 0.f, 0.f};
#pragma unroll
            for (int s = 0; s < 2; ++s) {
              shortx8 at = *(const shortx8*)&Qs[(ti * 16 + col) * 72 + s * 32 + quad * 8];
              shortx8 au = *(const shortx8*)&Qs[(ui * 16 + col) * 72 + s * 32 + quad * 8];
              sc = MFMA16(at, au, sc);
            }
#pragma unroll
            for (int r = 0; r < 4; ++r) {
              int t = ti * 16 + quad * 4 + r, u = ui * 16 + col;
              Ss[t * 72 + u] = (u < t) ? f2bf(sc[r]) : (unsigned short)0;
            }
          }
        }
    }
    __syncthreads();   // B2

    // ---- O accum: wave -> d-tiles {2w,2w+1}, all 4 t-tiles ----
    floatx4 acc[4][2];
#pragma unroll
    for (int ti = 0; ti < 4; ++ti)
#pragma unroll
      for (int dj = 0; dj < 2; ++dj) acc[ti][dj] = (floatx4){0.f, 0.f, 0.f, 0.f};

    // Q @ P (K=64 over i)
#pragma unroll
    for (int s = 0; s < 2; ++s) {
      const int koff = s * 32 + quad * 8;
      shortx8 bp[2];
#pragma unroll
      for (int dj = 0; dj < 2; ++dj)
        bp[dj] = lds8(&Pt[((wave * 2 + dj) * 16 + col) * 68 + koff]);
#pragma unroll
      for (int ti = 0; ti < 4; ++ti) {
        shortx8 aq = *(const shortx8*)&Qs[(ti * 16 + col) * 72 + koff];
#pragma unroll
        for (int dj = 0; dj < 2; ++dj) acc[ti][dj] = MFMA16(aq, bp[dj], acc[ti][dj]);
      }
    }
    // S @ V (skip all-zero upper K-steps)
#pragma unroll
    for (int s = 0; s < 2; ++s) {
      const int koff = s * 32 + quad * 8;
      shortx8 bv[2];
#pragma unroll
      for (int dj = 0; dj < 2; ++dj)
        bv[dj] = lds8(&Vt[((wave * 2 + dj) * 16 + col) * 68 + koff]);
      for (int ti = (s == 0 ? 0 : 2); ti < 4; ++ti) {
        shortx8 as = *(const shortx8*)&Ss[(ti * 16 + col) * 72 + koff];
#pragma unroll
        for (int dj = 0; dj < 2; ++dj) acc[ti][dj] = MFMA16(as, bv[dj], acc[ti][dj]);
      }
    }
    // store O chunk
#pragma unroll
    for (int ti = 0; ti < 4; ++ti)
#pragma unroll
      for (int dj = 0; dj < 2; ++dj)
#pragma unroll
        for (int r = 0; r < 4; ++r) {
          int t = c * 64 + ti * 16 + quad * 4 + r;
          int d = (wave * 2 + dj) * 16 + col;
          obase[(size_t)t * 1024 + d] = acc[ti][dj][r];
        }

    if (c == 0) {
      // ---- P += Q_0^T V_0 : U[d][i]; wave -> i-tile = wave, 8 d-tiles ----
      floatx4 ua[8];
#pragma unroll
      for (int dm = 0; dm < 8; ++dm) ua[dm] = (floatx4){0.f, 0.f, 0.f, 0.f};
#pragma unroll
      for (int s = 0; s < 2; ++s) {
        const int koff = s * 32 + quad * 8;
        shortx8 bq;                          // B[k=t][n=i] = Qs column (16 reads total)
#pragma unroll
        for (int jj = 0; jj < 8; ++jj)
          bq[jj] = (short)Qs[(koff + jj) * 72 + wave * 16 + col];
#pragma unroll
        for (int dm = 0; dm < 8; ++dm) {
          shortx8 av = lds8(&Vt[(dm * 16 + col) * 68 + koff]);
          ua[dm] = MFMA16(av, bq, ua[dm]);
        }
      }
      __syncthreads();  // B3: all Pt reads done before overwrite
#pragma unroll
      for (int dm = 0; dm < 8; ++dm)
#pragma unroll
        for (int r = 0; r < 4; ++r) {
          int d = dm * 16 + quad * 4 + r;
          int i = wave * 16 + col;
          int idx = d * 68 + i;
          Pt[idx] = f2bf(bf2f(Pt[idx]) + ua[dm][r]);
        }
      __syncthreads();  // B4: Pt update visible; Qs/Vt free for restage
    }
  }
}

// ---------------------------------------------------------------------------
extern "C" void kernel_launch(void* const* d_in, const int* in_sizes, int n_in,
                              void* d_out, int out_size, void* d_ws, size_t ws_size,
                              hipStream_t stream) {
  (void)in_sizes; (void)n_in; (void)out_size; (void)ws_size;
  const float* Q     = (const float*)d_in[0];
  const float* V     = (const float*)d_in[1];
  const float* state = (const float*)d_in[2];
  float* out        = (float*)d_out;
  float* new_state  = out + (size_t)4 * 2048 * 8 * 128;
  unsigned short* ws1 = (unsigned short*)d_ws;                              // 8.4 MB bf16 [i][d]
  unsigned short* ws2 = (unsigned short*)((char*)d_ws + (size_t)512 * 8192 * 2);  // 8.4 MB bf16

  k_phase1<<<512, 256, 0, stream>>>(Q, V, ws1);
  k_prefix<<<1024, 256, 0, stream>>>(state, ws1, ws2, new_state);
  k_phase2<<<512, 256, 0, stream>>>(Q, V, ws2, out);
}